// Round 18
// baseline (373.314 us; speedup 1.0000x reference)
//
#include <hip/hip_runtime.h>

typedef __attribute__((ext_vector_type(8))) __bf16 bf16x8;
typedef __attribute__((ext_vector_type(4))) float f32x4;

#define NH 32
#define DH 80
#define SEQ 1024
#define NB 4
#define NT 4096
#define HID 2560
#define NQKV 7680
#define SM_SCALE 0.11180339887498948f
#define QSCALE 0.16131381648337428f  // SM_SCALE * log2(e)

static __device__ __forceinline__ unsigned short f2bf(float f) {
  unsigned u = __builtin_bit_cast(unsigned, f);
  u += 0x7fffu + ((u >> 16) & 1u);
  return (unsigned short)(u >> 16);
}
static __device__ __forceinline__ float bf2f(unsigned short s) {
  unsigned u = (unsigned)s << 16;
  return __builtin_bit_cast(float, u);
}

typedef __attribute__((address_space(1))) const unsigned int as1_uint;
typedef __attribute__((address_space(3))) unsigned int as3_uint;
static __device__ __forceinline__ void gload16(const void* g, void* l) {
  __builtin_amdgcn_global_load_lds((as1_uint*)g, (as3_uint*)l, 16, 0, 0);
}

// ------- fp32 -> bf16 convert, 3 segments in ONE launch -------
__global__ __launch_bounds__(256) void cvt3_kernel(
    const float* __restrict__ s0, unsigned short* __restrict__ d0, int n0,
    const float* __restrict__ s1, unsigned short* __restrict__ d1, int n1,
    const float* __restrict__ s2, unsigned short* __restrict__ d2, int n2) {
  const int ntot = n0 + n1 + n2;
  for (int i = blockIdx.x * blockDim.x + threadIdx.x; i < ntot;
       i += gridDim.x * blockDim.x) {
    const float4* __restrict__ s;
    ushort4* __restrict__ d;
    int j;
    if (i < n0) {
      s = (const float4*)s0; d = (ushort4*)d0; j = i;
    } else if (i < n0 + n1) {
      s = (const float4*)s1; d = (ushort4*)d1; j = i - n0;
    } else {
      s = (const float4*)s2; d = (ushort4*)d2; j = i - n0 - n1;
    }
    float4 v = s[j];
    ushort4 o;
    o.x = f2bf(v.x);
    o.y = f2bf(v.y);
    o.z = f2bf(v.z);
    o.w = f2bf(v.w);
    d[j] = o;
  }
}

// ------------- 256x256 pipelined bf16 GEMM (QKV) — MINIMAL BARRIERS ---------
// Deep staging (stage t+2 into the current buffer, counted vmcnt(8) at
// boundaries); THREE barriers per K-tile:
//  B1 (lgkmcnt(0)+bar, post all-B-reads) -> SB(buf,t+2) safe
//  B2 (lgkmcnt(0)+bar, post all-A-reads) -> SA(buf,t+2) safe
//  B3 (boundary, vmcnt(8))               -> t+1 visible
// FA/FB take LOCAL rows within the wave's half (base already selects half).
template <int EPI>
__global__ __launch_bounds__(512, 2) void gemm8p_kernel(
    const unsigned short* __restrict__ A, const unsigned short* __restrict__ Bm,
    const float* __restrict__ bias, unsigned short* __restrict__ Cq,
    unsigned short* __restrict__ Ck, unsigned short* __restrict__ Cv,
    float* __restrict__ Cf, int M, int N, int K) {
  __shared__ __align__(16) unsigned short AL[2][2][8192];  // [buf][half][128*64]
  __shared__ __align__(16) unsigned short BL[2][2][8192];
  const int tid = threadIdx.x;
  const int lane = tid & 63, w = tid >> 6;
  const int wm = w >> 2, wn = w & 3;
  const int lr = lane & 15, lg = lane >> 4;
  const int bhh = wn >> 1;
  const int brow = (wn & 1) * 64;

  const int gx = gridDim.x;
  const int nwg = gx * gridDim.y;
  int bid = blockIdx.y * gx + blockIdx.x;
  bid = (bid & 7) * (nwg >> 3) + (bid >> 3);
  const int n0 = (bid % gx) * 256;
  const int m0 = (bid / gx) * 256;

  const unsigned short* asrc[2][2];
  const unsigned short* bsrc[2][2];
#pragma unroll
  for (int h = 0; h < 2; ++h)
#pragma unroll
    for (int j = 0; j < 2; ++j) {
      const int off = j * 8192 + tid * 16;
      const int u = off ^ (((off >> 7) & 7) << 4);
      const int row = u >> 7, col = (u & 127) >> 1;
      asrc[h][j] = A + (size_t)(m0 + h * 128 + row) * K + col;
      bsrc[h][j] = Bm + (size_t)(n0 + h * 128 + row) * K + col;
    }

  const int NK = K >> 6;

#define SA(buf, h, kt)                                                     \
  do {                                                                     \
    gload16(asrc[h][0] + (size_t)(kt) * 64,                                \
            (char*)&AL[buf][h][0] + w * 1024);                             \
    gload16(asrc[h][1] + (size_t)(kt) * 64,                                \
            (char*)&AL[buf][h][0] + 8192 + w * 1024);                      \
  } while (0)
#define SB(buf, h, kt)                                                     \
  do {                                                                     \
    gload16(bsrc[h][0] + (size_t)(kt) * 64,                                \
            (char*)&BL[buf][h][0] + w * 1024);                             \
    gload16(bsrc[h][1] + (size_t)(kt) * 64,                                \
            (char*)&BL[buf][h][0] + 8192 + w * 1024);                      \
  } while (0)
#define FA(buf, lrow, ks)                                                  \
  (*(const bf16x8*)((const char*)&AL[buf][wm][0] +                         \
                    (((lrow) * 128 + (ks) * 64 + lg * 16) ^                \
                     (((lrow) & 7) << 4))))
#define FB(buf, lrow, ks)                                                  \
  (*(const bf16x8*)((const char*)&BL[buf][bhh][0] +                        \
                    (((lrow) * 128 + (ks) * 64 + lg * 16) ^                \
                     (((lrow) & 7) << 4))))

  f32x4 acc[8][4];
#pragma unroll
  for (int i = 0; i < 8; ++i)
#pragma unroll
    for (int j = 0; j < 4; ++j) acc[i][j] = (f32x4)0.0f;

  // prologue: stage tile0 + tile1; wait t0 (counted); barrier
  SB(0, 0, 0); SB(0, 1, 0); SA(0, 0, 0); SA(0, 1, 0);
  SB(1, 0, 1); SB(1, 1, 1); SA(1, 0, 1); SA(1, 1, 1);
  asm volatile("s_waitcnt vmcnt(8)" ::: "memory");
  __builtin_amdgcn_s_barrier();

  for (int t = 0; t < NK; ++t) {
    const int buf = t & 1;
    const int tn = t + 2;
    const bool pf = tn < NK;
    bf16x8 af[8], blr[4], bhr[4];

    // ---- segment 1: A local rows 0-63 (both ks) + ALL B (both ks) ----
#pragma unroll
    for (int mf = 0; mf < 4; ++mf) {
      af[mf * 2 + 0] = FA(buf, mf * 16 + lr, 0);
      af[mf * 2 + 1] = FA(buf, mf * 16 + lr, 1);
    }
#pragma unroll
    for (int nf = 0; nf < 2; ++nf) {
      blr[nf * 2 + 0] = FB(buf, brow + nf * 16 + lr, 0);
      blr[nf * 2 + 1] = FB(buf, brow + nf * 16 + lr, 1);
      bhr[nf * 2 + 0] = FB(buf, brow + (nf + 2) * 16 + lr, 0);
      bhr[nf * 2 + 1] = FB(buf, brow + (nf + 2) * 16 + lr, 1);
    }
    __builtin_amdgcn_s_setprio(1);
#pragma unroll
    for (int mf = 0; mf < 4; ++mf)
#pragma unroll
      for (int nf = 0; nf < 2; ++nf) {
        acc[mf][nf] = __builtin_amdgcn_mfma_f32_16x16x32_bf16(
            af[mf * 2 + 0], blr[nf * 2 + 0], acc[mf][nf], 0, 0, 0);
        acc[mf][nf] = __builtin_amdgcn_mfma_f32_16x16x32_bf16(
            af[mf * 2 + 1], blr[nf * 2 + 1], acc[mf][nf], 0, 0, 0);
        acc[mf][nf + 2] = __builtin_amdgcn_mfma_f32_16x16x32_bf16(
            af[mf * 2 + 0], bhr[nf * 2 + 0], acc[mf][nf + 2], 0, 0, 0);
        acc[mf][nf + 2] = __builtin_amdgcn_mfma_f32_16x16x32_bf16(
            af[mf * 2 + 1], bhr[nf * 2 + 1], acc[mf][nf + 2], 0, 0, 0);
      }
    __builtin_amdgcn_s_setprio(0);
    asm volatile("s_waitcnt lgkmcnt(0)" ::: "memory");
    __builtin_amdgcn_s_barrier();  // B1: all waves' B reads complete
    if (pf) { SB(buf, 0, tn); SB(buf, 1, tn); }

    // ---- segment 2: A local rows 64-127 (both ks) ----
#pragma unroll
    for (int mf = 0; mf < 4; ++mf) {
      af[mf * 2 + 0] = FA(buf, 64 + mf * 16 + lr, 0);
      af[mf * 2 + 1] = FA(buf, 64 + mf * 16 + lr, 1);
    }
    __builtin_amdgcn_s_setprio(1);
#pragma unroll
    for (int mf = 0; mf < 4; ++mf)
#pragma unroll
      for (int nf = 0; nf < 2; ++nf) {
        acc[mf + 4][nf] = __builtin_amdgcn_mfma_f32_16x16x32_bf16(
            af[mf * 2 + 0], blr[nf * 2 + 0], acc[mf + 4][nf], 0, 0, 0);
        acc[mf + 4][nf] = __builtin_amdgcn_mfma_f32_16x16x32_bf16(
            af[mf * 2 + 1], blr[nf * 2 + 1], acc[mf + 4][nf], 0, 0, 0);
        acc[mf + 4][nf + 2] = __builtin_amdgcn_mfma_f32_16x16x32_bf16(
            af[mf * 2 + 0], bhr[nf * 2 + 0], acc[mf + 4][nf + 2], 0, 0, 0);
        acc[mf + 4][nf + 2] = __builtin_amdgcn_mfma_f32_16x16x32_bf16(
            af[mf * 2 + 1], bhr[nf * 2 + 1], acc[mf + 4][nf + 2], 0, 0, 0);
      }
    __builtin_amdgcn_s_setprio(0);
    asm volatile("s_waitcnt lgkmcnt(0)" ::: "memory");
    __builtin_amdgcn_s_barrier();  // B2: all waves' A reads complete
    if (pf) { SA(buf, 0, tn); SA(buf, 1, tn); }

    // ---- boundary: t+1 must be visible ----
    if (pf)
      asm volatile("s_waitcnt vmcnt(8)" ::: "memory");
    else if (t + 1 < NK)
      asm volatile("s_waitcnt vmcnt(0)" ::: "memory");
    __builtin_amdgcn_s_barrier();  // B3
  }
#undef SA
#undef SB
#undef FA
#undef FB

  if (EPI == 0) {
    if (n0 >= 2 * HID) {
      unsigned short* scr = (unsigned short*)&AL[0][0][0] + w * 2176;
      const int bb = (m0 + wm * 128) >> 10;
      const int ssb = (m0 + wm * 128) & 1023;
#pragma unroll
      for (int nf = 0; nf < 4; ++nf) {
        const int col0 = n0 - 2 * HID + wn * 64 + nf * 16;
        const int hh = col0 / DH;
        const int dd0 = col0 - hh * DH;
        const float bv = bias[2 * HID + col0 + lr];
#pragma unroll
        for (int mf = 0; mf < 8; ++mf) {
          ushort4 p;
          p.x = f2bf(acc[mf][nf][0] + bv);
          p.y = f2bf(acc[mf][nf][1] + bv);
          p.z = f2bf(acc[mf][nf][2] + bv);
          p.w = f2bf(acc[mf][nf][3] + bv);
          *(ushort4*)&scr[lr * 136 + mf * 16 + lg * 4] = p;
        }
#pragma unroll
        for (int it = 0; it < 4; ++it) {
          const int dd = (lane >> 4) + it * 4;
          const int sl = (lane & 15) * 8;
          bf16x8 v = *(const bf16x8*)&scr[dd * 136 + sl];
          *(bf16x8*)(Cv + ((size_t)(bb * NH + hh) * DH + dd0 + dd) * SEQ + ssb + sl) = v;
        }
        asm volatile("s_waitcnt lgkmcnt(0)" ::: "memory");
      }
    } else {
#pragma unroll
      for (int nf = 0; nf < 4; ++nf) {
        const int col = n0 + wn * 64 + nf * 16 + lr;
        const int sec = col >= HID ? 1 : 0;
        const int rem = col - sec * HID;
        const int hh = rem / DH;
        const int dd = rem - hh * DH;
        unsigned short* dst = sec ? Ck : Cq;
        const float bv = bias[col];
#pragma unroll
        for (int mf = 0; mf < 8; ++mf) {
#pragma unroll
          for (int r = 0; r < 4; ++r) {
            const int tr = m0 + wm * 128 + mf * 16 + lg * 4 + r;
            const int bb2 = tr >> 10, ss = tr & 1023;
            dst[((size_t)(bb2 * NH + hh) * SEQ + ss) * DH + dd] =
                f2bf(acc[mf][nf][r] + bv);
          }
        }
      }
    }
  } else {
#pragma unroll
    for (int nf = 0; nf < 4; ++nf) {
      const int col = n0 + wn * 64 + nf * 16 + lr;
      const float bv = bias[col];
#pragma unroll
      for (int mf = 0; mf < 8; ++mf)
#pragma unroll
        for (int r = 0; r < 4; ++r) {
          const int row = m0 + wm * 128 + mf * 16 + lg * 4 + r;
          Cf[row * N + col] = acc[mf][nf][r] + bv;
        }
    }
  }
}

// --------- dense GEMM: 128x320 tile, full-fill, ONE barrier per tile ---------
__global__ __launch_bounds__(512, 2) void gemmd8p_kernel(
    const unsigned short* __restrict__ A, const unsigned short* __restrict__ Bm,
    const float* __restrict__ bias, float* __restrict__ Cf, int M, int N, int K) {
  __shared__ __align__(16) unsigned short AL[2][8192];   // [buf][128 rows x 64k]
  __shared__ __align__(16) unsigned short BL[2][20480];  // [buf][320 rows x 64k]
  const int tid = threadIdx.x;
  const int lane = tid & 63, w = tid >> 6;
  const int wm = w >> 2, wn = w & 3;  // 2M x 4N; wave tile 64 x 80
  const int lr = lane & 15, lg = lane >> 4;

  const int gx = gridDim.x;  // 8
  const int nwg = gx * gridDim.y;
  int bid = blockIdx.y * gx + blockIdx.x;
  bid = (bid & 7) * (nwg >> 3) + (bid >> 3);
  const int n0 = (bid % gx) * 320;
  const int m0 = (bid / gx) * 128;

  const unsigned short* asrc[2];
  const unsigned short* bsrc[5];
#pragma unroll
  for (int j = 0; j < 2; ++j) {
    const int off = j * 8192 + tid * 16;
    const int u = off ^ (((off >> 7) & 7) << 4);
    const int row = u >> 7, col = (u & 127) >> 1;
    asrc[j] = A + (size_t)(m0 + row) * K + col;
  }
#pragma unroll
  for (int j = 0; j < 5; ++j) {
    const int off = j * 8192 + tid * 16;
    const int u = off ^ (((off >> 7) & 7) << 4);
    const int row = u >> 7, col = (u & 127) >> 1;
    bsrc[j] = Bm + (size_t)(n0 + row) * K + col;
  }

  const int NK = K >> 6;  // 40

#define DSTG(buf, kt)                                                       \
  do {                                                                      \
    gload16(asrc[0] + (size_t)(kt) * 64, (char*)&AL[buf][0] + tid * 16);    \
    gload16(asrc[1] + (size_t)(kt) * 64,                                    \
            (char*)&AL[buf][0] + 8192 + tid * 16);                          \
    gload16(bsrc[0] + (size_t)(kt) * 64, (char*)&BL[buf][0] + tid * 16);    \
    gload16(bsrc[1] + (size_t)(kt) * 64,                                    \
            (char*)&BL[buf][0] + 8192 + tid * 16);                          \
    gload16(bsrc[2] + (size_t)(kt) * 64,                                    \
            (char*)&BL[buf][0] + 16384 + tid * 16);                         \
    gload16(bsrc[3] + (size_t)(kt) * 64,                                    \
            (char*)&BL[buf][0] + 24576 + tid * 16);                         \
    gload16(bsrc[4] + (size_t)(kt) * 64,                                    \
            (char*)&BL[buf][0] + 32768 + tid * 16);                         \
  } while (0)
#define DFA(buf, lrow, ks)                                                  \
  (*(const bf16x8*)((const char*)&AL[buf][0] +                              \
                    (((lrow) * 128 + (ks) * 64 + lg * 16) ^                 \
                     (((lrow) & 7) << 4))))
#define DFB(buf, lrow, ks)                                                  \
  (*(const bf16x8*)((const char*)&BL[buf][0] +                              \
                    (((lrow) * 128 + (ks) * 64 + lg * 16) ^                 \
                     (((lrow) & 7) << 4))))

  f32x4 acc[4][5];
#pragma unroll
  for (int i = 0; i < 4; ++i)
#pragma unroll
    for (int j = 0; j < 5; ++j) acc[i][j] = (f32x4)0.0f;

  DSTG(0, 0);
  asm volatile("s_waitcnt vmcnt(0)" ::: "memory");
  __builtin_amdgcn_s_barrier();

  for (int t = 0; t < NK; ++t) {
    const int buf = t & 1, nb = buf ^ 1;
    const bool pf = (t + 1) < NK;
    if (pf) DSTG(nb, t + 1);  // dead buffer; issue first for latency cover

    bf16x8 afr[8], bfr[10];
#pragma unroll
    for (int mf = 0; mf < 4; ++mf) {
      afr[mf * 2 + 0] = DFA(buf, wm * 64 + mf * 16 + lr, 0);
      afr[mf * 2 + 1] = DFA(buf, wm * 64 + mf * 16 + lr, 1);
    }
#pragma unroll
    for (int nf = 0; nf < 5; ++nf) {
      bfr[nf * 2 + 0] = DFB(buf, wn * 80 + nf * 16 + lr, 0);
      bfr[nf * 2 + 1] = DFB(buf, wn * 80 + nf * 16 + lr, 1);
    }
    __builtin_amdgcn_s_setprio(1);
#pragma unroll
    for (int mf = 0; mf < 4; ++mf)
#pragma unroll
      for (int nf = 0; nf < 5; ++nf) {
        acc[mf][nf] = __builtin_amdgcn_mfma_f32_16x16x32_bf16(
            afr[mf * 2 + 0], bfr[nf * 2 + 0], acc[mf][nf], 0, 0, 0);
        acc[mf][nf] = __builtin_amdgcn_mfma_f32_16x16x32_bf16(
            afr[mf * 2 + 1], bfr[nf * 2 + 1], acc[mf][nf], 0, 0, 0);
      }
    __builtin_amdgcn_s_setprio(0);
    asm volatile("s_waitcnt lgkmcnt(0)" ::: "memory");
    if (pf) asm volatile("s_waitcnt vmcnt(0)" ::: "memory");
    __builtin_amdgcn_s_barrier();  // boundary: reads done + t+1 visible
  }
#undef DSTG
#undef DFA
#undef DFB

#pragma unroll
  for (int nf = 0; nf < 5; ++nf) {
    const int col = n0 + wn * 80 + nf * 16 + lr;
    const float bv = bias[col];
#pragma unroll
    for (int mf = 0; mf < 4; ++mf)
#pragma unroll
      for (int r = 0; r < 4; ++r) {
        const int row = m0 + wm * 64 + mf * 16 + lg * 4 + r;
        Cf[(size_t)row * N + col] = acc[mf][nf][r] + bv;
      }
  }
}

// ------- in-place partial rotary on Q,K; Q pre-scaled by SM_SCALE*log2e ------
__global__ __launch_bounds__(256) void rope_kernel(unsigned short* __restrict__ Q,
                                                   unsigned short* __restrict__ K,
                                                   const float* __restrict__ cosb,
                                                   const float* __restrict__ sinb) {
  const int idx = blockIdx.x * 256 + threadIdx.x;  // B*H*S*16
  const int i = idx & 15;
  const int s = (idx >> 4) & 1023;
  const int bh = idx >> 14;
  const int b = bh >> 5;
  const int t = b * SEQ + s;
  const float c = cosb[t * 16 + i];
  const float sn = sinb[t * 16 + i];
  const int base = (bh * SEQ + s) * DH;
  float q1 = bf2f(Q[base + i]), q2 = bf2f(Q[base + 16 + i]);
  Q[base + i] = f2bf((q1 * c - q2 * sn) * QSCALE);
  Q[base + 16 + i] = f2bf((q2 * c + q1 * sn) * QSCALE);
#pragma unroll
  for (int j = 0; j < 3; ++j) {
    const int d = 32 + j * 16 + i;
    Q[base + d] = f2bf(bf2f(Q[base + d]) * QSCALE);
  }
  float k1 = bf2f(K[base + i]), k2 = bf2f(K[base + 16 + i]);
  K[base + i] = f2bf(k1 * c - k2 * sn);
  K[base + 16 + i] = f2bf(k2 * c + k1 * sn);
}

// ------- flash attention (QBLK=256, 8 waves x 32 q-rows, causal-paired) -----
// (frozen; exp2-domain softmax, T13 defer-max, T14 async-stage)
__global__ __launch_bounds__(512) void attn_kernel(const unsigned short* __restrict__ Qb,
                                                   const unsigned short* __restrict__ Kb,
                                                   const unsigned short* __restrict__ Vg,
                                                   unsigned short* __restrict__ Ob) {
  __shared__ __align__(16) unsigned short Klds[64][104];  // D padded 80->96
  __shared__ __align__(16) unsigned short Vt[80][72];     // V^T tile [d][k]
  __shared__ __align__(16) unsigned short Plds[8][32][72];
  const int tid = threadIdx.x;
  const int lane = tid & 63, w = tid >> 6;
  const int lr = lane & 15, lg = lane >> 4;
  const int koff = lg * 8;
  const int bh = blockIdx.y;
  const int h = bh & 31;
  const int base = bh * (SEQ * DH);   // Q,K: [B][H][S][D]
  const int vbase = bh * (DH * SEQ);  // V:   [B][H][D][S]

  for (int e = tid; e < 64 * 16; e += 512) Klds[e >> 4][80 + (e & 15)] = 0;

  const int ke0r = tid / 10, ke0c = (tid - (tid / 10) * 10) * 8;
  const int ke1 = tid + 512;
  const int ke1r = ke1 / 10, ke1c = (ke1 - (ke1 / 10) * 10) * 8;
  const int ve0d = tid >> 3, ve0c = (tid & 7) * 8;
  const int ve1d = (tid + 512) >> 3, ve1c = ((tid + 512) & 7) * 8;

  const int qts[2] = {(int)blockIdx.x, 3 - (int)blockIdx.x};

  for (int sub = 0; sub < 2; ++sub) {
    const int qt = qts[sub];
    const int rowbase = qt * 256 + w * 32;

    bf16x8 qf[2][3];
#pragma unroll
    for (int hh = 0; hh < 2; ++hh)
#pragma unroll
      for (int c = 0; c < 3; ++c) {
        const int d = c * 32 + koff;
        if (d < DH)
          qf[hh][c] =
              *(const bf16x8*)(Qb + base + (rowbase + hh * 16 + lr) * DH + d);
        else
          qf[hh][c] = (bf16x8)(__bf16)0.0f;
      }

    float m[2][4], l[2][4];
    f32x4 of[2][5];
#pragma unroll
    for (int hh = 0; hh < 2; ++hh) {
#pragma unroll
      for (int r = 0; r < 4; ++r) {
        m[hh][r] = -3.0e38f;
        l[hh][r] = 0.0f;
      }
#pragma unroll
      for (int d = 0; d < 5; ++d) of[hh][d] = (f32x4)0.0f;
    }

    bf16x8 kreg0, kreg1, vreg0, vreg1;
    kreg0 = *(const bf16x8*)(Kb + base + ke0r * DH + ke0c);
    if (tid < 128) kreg1 = *(const bf16x8*)(Kb + base + ke1r * DH + ke1c);
    vreg0 = *(const bf16x8*)(Vg + vbase + ve0d * SEQ + ve0c);
    if (tid < 128) vreg1 = *(const bf16x8*)(Vg + vbase + ve1d * SEQ + ve1c);

    const int ktmax = 4 * qt + 3;
    for (int kt = 0; kt <= ktmax; ++kt) {
      __syncthreads();
      *(bf16x8*)&Klds[ke0r][ke0c] = kreg0;
      if (tid < 128) *(bf16x8*)&Klds[ke1r][ke1c] = kreg1;
      *(bf16x8*)&Vt[ve0d][ve0c] = vreg0;
      if (tid < 128) *(bf16x8*)&Vt[ve1d][ve1c] = vreg1;
      __syncthreads();

      if (kt < ktmax) {  // T14 async-stage
        const int nb = (kt + 1) * 64;
        kreg0 = *(const bf16x8*)(Kb + base + (nb + ke0r) * DH + ke0c);
        if (tid < 128) kreg1 = *(const bf16x8*)(Kb + base + (nb + ke1r) * DH + ke1c);
        vreg0 = *(const bf16x8*)(Vg + vbase + ve0d * SEQ + nb + ve0c);
        if (tid < 128) vreg1 = *(const bf16x8*)(Vg + vbase + ve1d * SEQ + nb + ve1c);
      }

      if (kt * 64 > rowbase + 31) continue;
      const bool fullvis = (kt * 64 + 63 <= rowbase);

      f32x4 sc[2][4];
#pragma unroll
      for (int hh = 0; hh < 2; ++hh)
#pragma unroll
        for (int cf = 0; cf < 4; ++cf) sc[hh][cf] = (f32x4)0.0f;
#pragma unroll
      for (int c = 0; c < 3; ++c) {
#pragma unroll
        for (int cf = 0; cf < 4; ++cf) {
          bf16x8 kb = *(const bf16x8*)&Klds[cf * 16 + lr][c * 32 + koff];
          sc[0][cf] = __builtin_amdgcn_mfma_f32_16x16x32_bf16(qf[0][c], kb, sc[0][cf], 0, 0, 0);
          sc[1][cf] = __builtin_amdgcn_mfma_f32_16x16x32_bf16(qf[1][c], kb, sc[1][cf], 0, 0, 0);
        }
      }

#pragma unroll
      for (int hh = 0; hh < 2; ++hh) {
        if (!fullvis) {
          const int rowg = rowbase + hh * 16 + lg * 4;
#pragma unroll
          for (int cf = 0; cf < 4; ++cf) {
            const int colg = kt * 64 + cf * 16 + lr;
#pragma unroll
            for (int r = 0; r < 4; ++r)
              if (colg > rowg + r) sc[hh][cf][r] = -1.0e30f;
          }
        }
        float mx[4];
#pragma unroll
        for (int r = 0; r < 4; ++r) {
          float v = fmaxf(fmaxf(sc[hh][0][r], sc[hh][1][r]),
                          fmaxf(sc[hh][2][r], sc[hh][3][r]));
#pragma unroll
          for (int off = 1; off < 16; off <<= 1) v = fmaxf(v, __shfl_xor(v, off, 64));
          mx[r] = v;
        }
        bool need = false;  // T13 defer-max (log2 domain: 11.54 == e^8 bound)
#pragma unroll
        for (int r = 0; r < 4; ++r) need |= (mx[r] > m[hh][r] + 11.54f);
        if (__ballot(need)) {
          float al[4];
#pragma unroll
          for (int r = 0; r < 4; ++r) {
            const float mn = fmaxf(m[hh][r], mx[r]);
            al[r] = exp2f(m[hh][r] - mn);
            m[hh][r] = mn;
          }
#pragma unroll
          for (int d = 0; d < 5; ++d)
#pragma unroll
            for (int r = 0; r < 4; ++r) of[hh][d][r] *= al[r];
#pragma unroll
          for (int r = 0; r < 4; ++r) l[hh][r] *= al[r];
        }
        float ls[4] = {0.f, 0.f, 0.f, 0.f};
#pragma unroll
        for (int cf = 0; cf < 4; ++cf)
#pragma unroll
          for (int r = 0; r < 4; ++r) {
            const float p = exp2f(sc[hh][cf][r] - m[hh][r]);
            sc[hh][cf][r] = p;
            ls[r] += p;
          }
#pragma unroll
        for (int r = 0; r < 4; ++r) {
          float sv = ls[r];
#pragma unroll
          for (int off = 1; off < 16; off <<= 1) sv += __shfl_xor(sv, off, 64);
          l[hh][r] += sv;
        }
#pragma unroll
        for (int cf = 0; cf < 4; ++cf)
#pragma unroll
          for (int r = 0; r < 4; ++r)
            Plds[w][hh * 16 + lg * 4 + r][cf * 16 + lr] = f2bf(sc[hh][cf][r]);
      }

#pragma unroll
      for (int kc = 0; kc < 2; ++kc) {
        bf16x8 pa0 = *(const bf16x8*)&Plds[w][lr][kc * 32 + koff];
        bf16x8 pa1 = *(const bf16x8*)&Plds[w][16 + lr][kc * 32 + koff];
#pragma unroll
        for (int d = 0; d < 5; ++d) {
          bf16x8 vb = *(const bf16x8*)&Vt[d * 16 + lr][kc * 32 + koff];
          of[0][d] = __builtin_amdgcn_mfma_f32_16x16x32_bf16(pa0, vb, of[0][d], 0, 0, 0);
          of[1][d] = __builtin_amdgcn_mfma_f32_16x16x32_bf16(pa1, vb, of[1][d], 0, 0, 0);
        }
      }
    }

#pragma unroll
    for (int hh = 0; hh < 2; ++hh) {
      const int t = (bh >> 5) * SEQ + rowbase + hh * 16 + lg * 4;
#pragma unroll
      for (int r = 0; r < 4; ++r) {
        const float rl = 1.0f / l[hh][r];
#pragma unroll
        for (int d = 0; d < 5; ++d)
          Ob[(t + r) * HID + h * DH + d * 16 + lr] = f2bf(of[hh][d][r] * rl);
      }
    }
  }
}

// ---------------- launch ----------------
extern "C" void kernel_launch(void* const* d_in, const int* in_sizes, int n_in,
                              void* d_out, int out_size, void* d_ws, size_t ws_size,
                              hipStream_t stream) {
  const float* hs = (const float*)d_in[0];
  const float* cosb = (const float*)d_in[1];
  const float* sinb = (const float*)d_in[2];
  const float* w_qkv = (const float*)d_in[3];
  const float* b_qkv = (const float*)d_in[4];
  const float* w_dense = (const float*)d_in[5];
  const float* b_dense = (const float*)d_in[6];
  float* out = (float*)d_out;
  char* ws = (char*)d_ws;

  unsigned short* hsb = (unsigned short*)(ws + 0);          // 21.0 MB
  unsigned short* aob = (unsigned short*)(ws + 0);          // alias (attn out)
  unsigned short* wqb = (unsigned short*)(ws + 20971520);   // 39.3 MB
  unsigned short* wdb2 = (unsigned short*)(ws + 123207680); // 13.1 MB (dense W)
  unsigned short* Qb = (unsigned short*)(ws + 60293120);    // 21.0 MB
  unsigned short* Kb = (unsigned short*)(ws + 81264640);    // 21.0 MB
  unsigned short* Vb = (unsigned short*)(ws + 102236160);   // 21.0 MB ([B][H][D][S])

  cvt3_kernel<<<2048, 256, 0, stream>>>(hs, hsb, (NT * HID) / 4,
                                        w_qkv, wqb, (NQKV * HID) / 4,
                                        w_dense, wdb2, (HID * HID) / 4);
  gemm8p_kernel<0><<<dim3(NQKV / 256, NT / 256), 512, 0, stream>>>(
      hsb, wqb, b_qkv, Qb, Kb, Vb, nullptr, NT, NQKV, HID);
  rope_kernel<<<(NB * NH * SEQ * 16) / 256, 256, 0, stream>>>(Qb, Kb, cosb, sinb);
  attn_kernel<<<dim3(2, NB * NH), 512, 0, stream>>>(Qb, Kb, Vb, aob);
  gemmd8p_kernel<<<dim3(HID / 320, NT / 128), 512, 0, stream>>>(
      aob, wdb2, b_dense, out, NT, HID, HID);
}

// Round 19
// 347.341 us; speedup vs baseline: 1.0748x; 1.0748x over previous
//
#include <hip/hip_runtime.h>

typedef __attribute__((ext_vector_type(8))) __bf16 bf16x8;
typedef __attribute__((ext_vector_type(4))) float f32x4;

#define NH 32
#define DH 80
#define SEQ 1024
#define NB 4
#define NT 4096
#define HID 2560
#define NQKV 7680
#define SM_SCALE 0.11180339887498948f
#define QSCALE 0.16131381648337428f  // SM_SCALE * log2(e)

static __device__ __forceinline__ unsigned short f2bf(float f) {
  unsigned u = __builtin_bit_cast(unsigned, f);
  u += 0x7fffu + ((u >> 16) & 1u);
  return (unsigned short)(u >> 16);
}
static __device__ __forceinline__ float bf2f(unsigned short s) {
  unsigned u = (unsigned)s << 16;
  return __builtin_bit_cast(float, u);
}

typedef __attribute__((address_space(1))) const unsigned int as1_uint;
typedef __attribute__((address_space(3))) unsigned int as3_uint;
static __device__ __forceinline__ void gload16(const void* g, void* l) {
  __builtin_amdgcn_global_load_lds((as1_uint*)g, (as3_uint*)l, 16, 0, 0);
}

// ------- fp32 -> bf16 convert, 3 segments in ONE launch -------
__global__ __launch_bounds__(256) void cvt3_kernel(
    const float* __restrict__ s0, unsigned short* __restrict__ d0, int n0,
    const float* __restrict__ s1, unsigned short* __restrict__ d1, int n1,
    const float* __restrict__ s2, unsigned short* __restrict__ d2, int n2) {
  const int ntot = n0 + n1 + n2;
  for (int i = blockIdx.x * blockDim.x + threadIdx.x; i < ntot;
       i += gridDim.x * blockDim.x) {
    const float4* __restrict__ s;
    ushort4* __restrict__ d;
    int j;
    if (i < n0) {
      s = (const float4*)s0; d = (ushort4*)d0; j = i;
    } else if (i < n0 + n1) {
      s = (const float4*)s1; d = (ushort4*)d1; j = i - n0;
    } else {
      s = (const float4*)s2; d = (ushort4*)d2; j = i - n0 - n1;
    }
    float4 v = s[j];
    ushort4 o;
    o.x = f2bf(v.x);
    o.y = f2bf(v.y);
    o.z = f2bf(v.z);
    o.w = f2bf(v.w);
    d[j] = o;
  }
}

// ------------- 256x256 8-phase pipelined bf16 GEMM (QKV) -------------
// (round-11 structure — 177-180us steady, MfmaUtil 38%. FROZEN.)
template <int EPI>
__global__ __launch_bounds__(512, 2) void gemm8p_kernel(
    const unsigned short* __restrict__ A, const unsigned short* __restrict__ Bm,
    const float* __restrict__ bias, unsigned short* __restrict__ Cq,
    unsigned short* __restrict__ Ck, unsigned short* __restrict__ Cv,
    float* __restrict__ Cf, int M, int N, int K) {
  __shared__ __align__(16) unsigned short AL[2][2][8192];  // [buf][half][128*64]
  __shared__ __align__(16) unsigned short BL[2][2][8192];
  const int tid = threadIdx.x;
  const int lane = tid & 63, w = tid >> 6;
  const int wm = w >> 2, wn = w & 3;
  const int lr = lane & 15, lg = lane >> 4;
  const int bhh = wn >> 1;
  const int brow = (wn & 1) * 64;

  const int gx = gridDim.x;
  const int nwg = gx * gridDim.y;
  int bid = blockIdx.y * gx + blockIdx.x;
  bid = (bid & 7) * (nwg >> 3) + (bid >> 3);
  const int n0 = (bid % gx) * 256;
  const int m0 = (bid / gx) * 256;

  const unsigned short* asrc[2][2];
  const unsigned short* bsrc[2][2];
#pragma unroll
  for (int h = 0; h < 2; ++h)
#pragma unroll
    for (int j = 0; j < 2; ++j) {
      const int off = j * 8192 + tid * 16;
      const int u = off ^ (((off >> 7) & 7) << 4);
      const int row = u >> 7, col = (u & 127) >> 1;
      asrc[h][j] = A + (size_t)(m0 + h * 128 + row) * K + col;
      bsrc[h][j] = Bm + (size_t)(n0 + h * 128 + row) * K + col;
    }

  const int NK = K >> 6, NIT = NK >> 1;

#define SA(buf, h, kt)                                                     \
  do {                                                                     \
    gload16(asrc[h][0] + (size_t)(kt) * 64,                                \
            (char*)&AL[buf][h][0] + w * 1024);                             \
    gload16(asrc[h][1] + (size_t)(kt) * 64,                                \
            (char*)&AL[buf][h][0] + 8192 + w * 1024);                      \
  } while (0)
#define SB(buf, h, kt)                                                     \
  do {                                                                     \
    gload16(bsrc[h][0] + (size_t)(kt) * 64,                                \
            (char*)&BL[buf][h][0] + w * 1024);                             \
    gload16(bsrc[h][1] + (size_t)(kt) * 64,                                \
            (char*)&BL[buf][h][0] + 8192 + w * 1024);                      \
  } while (0)
#define FA(buf, lrow, ks)                                                  \
  (*(const bf16x8*)((const char*)&AL[buf][wm][0] +                         \
                    (((lrow) * 128 + (ks) * 64 + lg * 16) ^                \
                     (((lrow) & 7) << 4))))
#define FB(buf, lrow, ks)                                                  \
  (*(const bf16x8*)((const char*)&BL[buf][bhh][0] +                        \
                    (((lrow) * 128 + (ks) * 64 + lg * 16) ^                \
                     (((lrow) & 7) << 4))))
#define PH_MFMA(AIDX, NBASE, BREG)                                         \
  __builtin_amdgcn_s_barrier();                                            \
  __builtin_amdgcn_s_setprio(1);                                           \
  _Pragma("unroll") for (int mf = 0; mf < 4; ++mf)                         \
      _Pragma("unroll") for (int nf = 0; nf < 2; ++nf) {                   \
    acc[AIDX + mf][NBASE + nf] = __builtin_amdgcn_mfma_f32_16x16x32_bf16(  \
        af[mf * 2 + 0], BREG[nf * 2 + 0], acc[AIDX + mf][NBASE + nf], 0, 0, 0); \
    acc[AIDX + mf][NBASE + nf] = __builtin_amdgcn_mfma_f32_16x16x32_bf16(  \
        af[mf * 2 + 1], BREG[nf * 2 + 1], acc[AIDX + mf][NBASE + nf], 0, 0, 0); \
  }                                                                        \
  __builtin_amdgcn_s_setprio(0);

  f32x4 acc[8][4];
#pragma unroll
  for (int i = 0; i < 8; ++i)
#pragma unroll
    for (int j = 0; j < 4; ++j) acc[i][j] = (f32x4)0.0f;

  SB(0, 0, 0); SB(0, 1, 0); SA(0, 0, 0); SA(0, 1, 0);
  SB(1, 0, 1); SB(1, 1, 1); SA(1, 0, 1); SA(1, 1, 1);
  asm volatile("s_waitcnt vmcnt(8)" ::: "memory");
  __builtin_amdgcn_s_barrier();

  bf16x8 af[8], bl[4], bhf[4];

  for (int i = 0; i < NIT; ++i) {
    const int t2 = 2 * i + 2, t3 = 2 * i + 3;
    const bool pf = (i + 1) < NIT;

#pragma unroll
    for (int mf = 0; mf < 4; ++mf) {
      af[mf * 2 + 0] = FA(0, mf * 16 + lr, 0);
      af[mf * 2 + 1] = FA(0, mf * 16 + lr, 1);
    }
#pragma unroll
    for (int nf = 0; nf < 2; ++nf) {
      bl[nf * 2 + 0] = FB(0, brow + nf * 16 + lr, 0);
      bl[nf * 2 + 1] = FB(0, brow + nf * 16 + lr, 1);
    }
    PH_MFMA(0, 0, bl)
    __builtin_amdgcn_s_barrier();
#pragma unroll
    for (int nf = 0; nf < 2; ++nf) {
      bhf[nf * 2 + 0] = FB(0, brow + (nf + 2) * 16 + lr, 0);
      bhf[nf * 2 + 1] = FB(0, brow + (nf + 2) * 16 + lr, 1);
    }
    PH_MFMA(0, 2, bhf)
    __builtin_amdgcn_s_barrier();
#pragma unroll
    for (int mf = 0; mf < 4; ++mf) {
      af[mf * 2 + 0] = FA(0, 64 + mf * 16 + lr, 0);
      af[mf * 2 + 1] = FA(0, 64 + mf * 16 + lr, 1);
    }
    if (pf) { SB(0, 0, t2); SB(0, 1, t2); }
    PH_MFMA(4, 0, bl)
    __builtin_amdgcn_s_barrier();
    if (pf) { SA(0, 0, t2); SA(0, 1, t2); }
    PH_MFMA(4, 2, bhf)
    if (pf)
      asm volatile("s_waitcnt vmcnt(8)" ::: "memory");
    else
      asm volatile("s_waitcnt vmcnt(0)" ::: "memory");
    __builtin_amdgcn_s_barrier();

#pragma unroll
    for (int mf = 0; mf < 4; ++mf) {
      af[mf * 2 + 0] = FA(1, mf * 16 + lr, 0);
      af[mf * 2 + 1] = FA(1, mf * 16 + lr, 1);
    }
#pragma unroll
    for (int nf = 0; nf < 2; ++nf) {
      bl[nf * 2 + 0] = FB(1, brow + nf * 16 + lr, 0);
      bl[nf * 2 + 1] = FB(1, brow + nf * 16 + lr, 1);
    }
    PH_MFMA(0, 0, bl)
    __builtin_amdgcn_s_barrier();
#pragma unroll
    for (int nf = 0; nf < 2; ++nf) {
      bhf[nf * 2 + 0] = FB(1, brow + (nf + 2) * 16 + lr, 0);
      bhf[nf * 2 + 1] = FB(1, brow + (nf + 2) * 16 + lr, 1);
    }
    PH_MFMA(0, 2, bhf)
    __builtin_amdgcn_s_barrier();
#pragma unroll
    for (int mf = 0; mf < 4; ++mf) {
      af[mf * 2 + 0] = FA(1, 64 + mf * 16 + lr, 0);
      af[mf * 2 + 1] = FA(1, 64 + mf * 16 + lr, 1);
    }
    if (pf) { SB(1, 0, t3); SB(1, 1, t3); }
    PH_MFMA(4, 0, bl)
    __builtin_amdgcn_s_barrier();
    if (pf) { SA(1, 0, t3); SA(1, 1, t3); }
    PH_MFMA(4, 2, bhf)
    if (pf) asm volatile("s_waitcnt vmcnt(8)" ::: "memory");
    __builtin_amdgcn_s_barrier();
  }
#undef SA
#undef SB
#undef FA
#undef FB
#undef PH_MFMA

  if (EPI == 0) {
    if (n0 >= 2 * HID) {
      unsigned short* scr = (unsigned short*)&AL[0][0][0] + w * 2176;
      const int bb = (m0 + wm * 128) >> 10;
      const int ssb = (m0 + wm * 128) & 1023;
#pragma unroll
      for (int nf = 0; nf < 4; ++nf) {
        const int col0 = n0 - 2 * HID + wn * 64 + nf * 16;
        const int hh = col0 / DH;
        const int dd0 = col0 - hh * DH;
        const float bv = bias[2 * HID + col0 + lr];
#pragma unroll
        for (int mf = 0; mf < 8; ++mf) {
          ushort4 p;
          p.x = f2bf(acc[mf][nf][0] + bv);
          p.y = f2bf(acc[mf][nf][1] + bv);
          p.z = f2bf(acc[mf][nf][2] + bv);
          p.w = f2bf(acc[mf][nf][3] + bv);
          *(ushort4*)&scr[lr * 136 + mf * 16 + lg * 4] = p;
        }
#pragma unroll
        for (int it = 0; it < 4; ++it) {
          const int dd = (lane >> 4) + it * 4;
          const int sl = (lane & 15) * 8;
          bf16x8 v = *(const bf16x8*)&scr[dd * 136 + sl];
          *(bf16x8*)(Cv + ((size_t)(bb * NH + hh) * DH + dd0 + dd) * SEQ + ssb + sl) = v;
        }
        asm volatile("s_waitcnt lgkmcnt(0)" ::: "memory");
      }
    } else {
#pragma unroll
      for (int nf = 0; nf < 4; ++nf) {
        const int col = n0 + wn * 64 + nf * 16 + lr;
        const int sec = col >= HID ? 1 : 0;
        const int rem = col - sec * HID;
        const int hh = rem / DH;
        const int dd = rem - hh * DH;
        unsigned short* dst = sec ? Ck : Cq;
        const float bv = bias[col];
#pragma unroll
        for (int mf = 0; mf < 8; ++mf) {
#pragma unroll
          for (int r = 0; r < 4; ++r) {
            const int tr = m0 + wm * 128 + mf * 16 + lg * 4 + r;
            const int bb2 = tr >> 10, ss = tr & 1023;
            dst[((size_t)(bb2 * NH + hh) * SEQ + ss) * DH + dd] =
                f2bf(acc[mf][nf][r] + bv);
          }
        }
      }
    }
  } else {
#pragma unroll
    for (int nf = 0; nf < 4; ++nf) {
      const int col = n0 + wn * 64 + nf * 16 + lr;
      const float bv = bias[col];
#pragma unroll
      for (int mf = 0; mf < 8; ++mf)
#pragma unroll
        for (int r = 0; r < 4; ++r) {
          const int row = m0 + wm * 128 + mf * 16 + lg * 4 + r;
          Cf[row * N + col] = acc[mf][nf][r] + bv;
        }
    }
  }
}

// --------- dense GEMM: 128x320 tile, full-fill (grid 8x32 = 256 = 1/CU) -----
__global__ __launch_bounds__(512, 2) void gemmd8p_kernel(
    const unsigned short* __restrict__ A, const unsigned short* __restrict__ Bm,
    const float* __restrict__ bias, float* __restrict__ Cf, int M, int N, int K) {
  __shared__ __align__(16) unsigned short AL[2][8192];   // [buf][128 rows x 64k]
  __shared__ __align__(16) unsigned short BL[2][20480];  // [buf][320 rows x 64k]
  const int tid = threadIdx.x;
  const int lane = tid & 63, w = tid >> 6;
  const int wm = w >> 2, wn = w & 3;  // 2M x 4N; wave tile 64 x 80
  const int lr = lane & 15, lg = lane >> 4;

  const int gx = gridDim.x;  // 8
  const int nwg = gx * gridDim.y;
  int bid = blockIdx.y * gx + blockIdx.x;
  bid = (bid & 7) * (nwg >> 3) + (bid >> 3);
  const int n0 = (bid % gx) * 320;
  const int m0 = (bid / gx) * 128;

  const unsigned short* asrc[2];
  const unsigned short* bsrc[5];
#pragma unroll
  for (int j = 0; j < 2; ++j) {
    const int off = j * 8192 + tid * 16;
    const int u = off ^ (((off >> 7) & 7) << 4);
    const int row = u >> 7, col = (u & 127) >> 1;
    asrc[j] = A + (size_t)(m0 + row) * K + col;
  }
#pragma unroll
  for (int j = 0; j < 5; ++j) {
    const int off = j * 8192 + tid * 16;
    const int u = off ^ (((off >> 7) & 7) << 4);
    const int row = u >> 7, col = (u & 127) >> 1;
    bsrc[j] = Bm + (size_t)(n0 + row) * K + col;
  }

  const int NK = K >> 6;  // 40

#define DSTG(buf, kt)                                                       \
  do {                                                                      \
    gload16(asrc[0] + (size_t)(kt) * 64, (char*)&AL[buf][0] + tid * 16);    \
    gload16(asrc[1] + (size_t)(kt) * 64,                                    \
            (char*)&AL[buf][0] + 8192 + tid * 16);                          \
    gload16(bsrc[0] + (size_t)(kt) * 64, (char*)&BL[buf][0] + tid * 16);    \
    gload16(bsrc[1] + (size_t)(kt) * 64,                                    \
            (char*)&BL[buf][0] + 8192 + tid * 16);                          \
    gload16(bsrc[2] + (size_t)(kt) * 64,                                    \
            (char*)&BL[buf][0] + 16384 + tid * 16);                         \
    gload16(bsrc[3] + (size_t)(kt) * 64,                                    \
            (char*)&BL[buf][0] + 24576 + tid * 16);                         \
    gload16(bsrc[4] + (size_t)(kt) * 64,                                    \
            (char*)&BL[buf][0] + 32768 + tid * 16);                         \
  } while (0)
#define DFA(buf, lrow, ks)                                                  \
  (*(const bf16x8*)((const char*)&AL[buf][0] +                              \
                    (((lrow) * 128 + (ks) * 64 + lg * 16) ^                 \
                     (((lrow) & 7) << 4))))
#define DFB(buf, lrow, ks)                                                  \
  (*(const bf16x8*)((const char*)&BL[buf][0] +                              \
                    (((lrow) * 128 + (ks) * 64 + lg * 16) ^                 \
                     (((lrow) & 7) << 4))))

  f32x4 acc[4][5];
#pragma unroll
  for (int i = 0; i < 4; ++i)
#pragma unroll
    for (int j = 0; j < 5; ++j) acc[i][j] = (f32x4)0.0f;

  DSTG(0, 0);
  asm volatile("s_waitcnt vmcnt(0)" ::: "memory");
  __builtin_amdgcn_s_barrier();

  for (int t = 0; t < NK; ++t) {
    const int buf = t & 1, nb = buf ^ 1;
    const bool pf = (t + 1) < NK;
    bf16x8 afr[4], bfr[5];

    // ---- phase 1: ks=0; stage ALL of tile t+1 into the dead buffer ----
#pragma unroll
    for (int mf = 0; mf < 4; ++mf) afr[mf] = DFA(buf, wm * 64 + mf * 16 + lr, 0);
#pragma unroll
    for (int nf = 0; nf < 5; ++nf) bfr[nf] = DFB(buf, wn * 80 + nf * 16 + lr, 0);
    if (pf) DSTG(nb, t + 1);
    __builtin_amdgcn_s_barrier();
    __builtin_amdgcn_s_setprio(1);
#pragma unroll
    for (int mf = 0; mf < 4; ++mf)
#pragma unroll
      for (int nf = 0; nf < 5; ++nf)
        acc[mf][nf] = __builtin_amdgcn_mfma_f32_16x16x32_bf16(afr[mf], bfr[nf],
                                                              acc[mf][nf], 0, 0, 0);
    __builtin_amdgcn_s_setprio(0);
    __builtin_amdgcn_s_barrier();

    // ---- phase 2: ks=1 ----
#pragma unroll
    for (int mf = 0; mf < 4; ++mf) afr[mf] = DFA(buf, wm * 64 + mf * 16 + lr, 1);
#pragma unroll
    for (int nf = 0; nf < 5; ++nf) bfr[nf] = DFB(buf, wn * 80 + nf * 16 + lr, 1);
    __builtin_amdgcn_s_barrier();
    __builtin_amdgcn_s_setprio(1);
#pragma unroll
    for (int mf = 0; mf < 4; ++mf)
#pragma unroll
      for (int nf = 0; nf < 5; ++nf)
        acc[mf][nf] = __builtin_amdgcn_mfma_f32_16x16x32_bf16(afr[mf], bfr[nf],
                                                              acc[mf][nf], 0, 0, 0);
    __builtin_amdgcn_s_setprio(0);
    if (pf) asm volatile("s_waitcnt vmcnt(0)" ::: "memory");
    __builtin_amdgcn_s_barrier();
  }
#undef DSTG
#undef DFA
#undef DFB

#pragma unroll
  for (int nf = 0; nf < 5; ++nf) {
    const int col = n0 + wn * 80 + nf * 16 + lr;
    const float bv = bias[col];
#pragma unroll
    for (int mf = 0; mf < 4; ++mf)
#pragma unroll
      for (int r = 0; r < 4; ++r) {
        const int row = m0 + wm * 64 + mf * 16 + lg * 4 + r;
        Cf[(size_t)row * N + col] = acc[mf][nf][r] + bv;
      }
  }
}

// ------- in-place partial rotary on Q,K; Q pre-scaled by SM_SCALE*log2e ------
__global__ __launch_bounds__(256) void rope_kernel(unsigned short* __restrict__ Q,
                                                   unsigned short* __restrict__ K,
                                                   const float* __restrict__ cosb,
                                                   const float* __restrict__ sinb) {
  const int idx = blockIdx.x * 256 + threadIdx.x;  // B*H*S*16
  const int i = idx & 15;
  const int s = (idx >> 4) & 1023;
  const int bh = idx >> 14;
  const int b = bh >> 5;
  const int t = b * SEQ + s;
  const float c = cosb[t * 16 + i];
  const float sn = sinb[t * 16 + i];
  const int base = (bh * SEQ + s) * DH;
  float q1 = bf2f(Q[base + i]), q2 = bf2f(Q[base + 16 + i]);
  Q[base + i] = f2bf((q1 * c - q2 * sn) * QSCALE);
  Q[base + 16 + i] = f2bf((q2 * c + q1 * sn) * QSCALE);
#pragma unroll
  for (int j = 0; j < 3; ++j) {
    const int d = 32 + j * 16 + i;
    Q[base + d] = f2bf(bf2f(Q[base + d]) * QSCALE);
  }
  float k1 = bf2f(K[base + i]), k2 = bf2f(K[base + 16 + i]);
  K[base + i] = f2bf(k1 * c - k2 * sn);
  K[base + 16 + i] = f2bf(k2 * c + k1 * sn);
}

// ------- flash attention (QBLK=256, 8 waves x 32 q-rows, causal-paired) -----
__global__ __launch_bounds__(512) void attn_kernel(const unsigned short* __restrict__ Qb,
                                                   const unsigned short* __restrict__ Kb,
                                                   const unsigned short* __restrict__ Vg,
                                                   unsigned short* __restrict__ Ob) {
  __shared__ __align__(16) unsigned short Klds[64][104];  // D padded 80->96
  __shared__ __align__(16) unsigned short Vt[80][72];     // V^T tile [d][k]
  __shared__ __align__(16) unsigned short Plds[8][32][72];
  const int tid = threadIdx.x;
  const int lane = tid & 63, w = tid >> 6;
  const int lr = lane & 15, lg = lane >> 4;
  const int koff = lg * 8;
  const int bh = blockIdx.y;
  const int h = bh & 31;
  const int base = bh * (SEQ * DH);   // Q,K: [B][H][S][D]
  const int vbase = bh * (DH * SEQ);  // V:   [B][H][D][S]

  for (int e = tid; e < 64 * 16; e += 512) Klds[e >> 4][80 + (e & 15)] = 0;

  const int ke0r = tid / 10, ke0c = (tid - (tid / 10) * 10) * 8;
  const int ke1 = tid + 512;
  const int ke1r = ke1 / 10, ke1c = (ke1 - (ke1 / 10) * 10) * 8;
  const int ve0d = tid >> 3, ve0c = (tid & 7) * 8;
  const int ve1d = (tid + 512) >> 3, ve1c = ((tid + 512) & 7) * 8;

  const int qts[2] = {(int)blockIdx.x, 3 - (int)blockIdx.x};

  for (int sub = 0; sub < 2; ++sub) {
    const int qt = qts[sub];
    const int rowbase = qt * 256 + w * 32;

    bf16x8 qf[2][3];
#pragma unroll
    for (int hh = 0; hh < 2; ++hh)
#pragma unroll
      for (int c = 0; c < 3; ++c) {
        const int d = c * 32 + koff;
        if (d < DH)
          qf[hh][c] =
              *(const bf16x8*)(Qb + base + (rowbase + hh * 16 + lr) * DH + d);
        else
          qf[hh][c] = (bf16x8)(__bf16)0.0f;
      }

    float m[2][4], l[2][4];
    f32x4 of[2][5];
#pragma unroll
    for (int hh = 0; hh < 2; ++hh) {
#pragma unroll
      for (int r = 0; r < 4; ++r) {
        m[hh][r] = -3.0e38f;
        l[hh][r] = 0.0f;
      }
#pragma unroll
      for (int d = 0; d < 5; ++d) of[hh][d] = (f32x4)0.0f;
    }

    bf16x8 kreg0, kreg1, vreg0, vreg1;
    kreg0 = *(const bf16x8*)(Kb + base + ke0r * DH + ke0c);
    if (tid < 128) kreg1 = *(const bf16x8*)(Kb + base + ke1r * DH + ke1c);
    vreg0 = *(const bf16x8*)(Vg + vbase + ve0d * SEQ + ve0c);
    if (tid < 128) vreg1 = *(const bf16x8*)(Vg + vbase + ve1d * SEQ + ve1c);

    const int ktmax = 4 * qt + 3;
    for (int kt = 0; kt <= ktmax; ++kt) {
      __syncthreads();
      *(bf16x8*)&Klds[ke0r][ke0c] = kreg0;
      if (tid < 128) *(bf16x8*)&Klds[ke1r][ke1c] = kreg1;
      *(bf16x8*)&Vt[ve0d][ve0c] = vreg0;
      if (tid < 128) *(bf16x8*)&Vt[ve1d][ve1c] = vreg1;
      __syncthreads();

      if (kt < ktmax) {  // T14 async-stage
        const int nb = (kt + 1) * 64;
        kreg0 = *(const bf16x8*)(Kb + base + (nb + ke0r) * DH + ke0c);
        if (tid < 128) kreg1 = *(const bf16x8*)(Kb + base + (nb + ke1r) * DH + ke1c);
        vreg0 = *(const bf16x8*)(Vg + vbase + ve0d * SEQ + nb + ve0c);
        if (tid < 128) vreg1 = *(const bf16x8*)(Vg + vbase + ve1d * SEQ + nb + ve1c);
      }

      if (kt * 64 > rowbase + 31) continue;
      const bool fullvis = (kt * 64 + 63 <= rowbase);

      f32x4 sc[2][4];
#pragma unroll
      for (int hh = 0; hh < 2; ++hh)
#pragma unroll
        for (int cf = 0; cf < 4; ++cf) sc[hh][cf] = (f32x4)0.0f;
#pragma unroll
      for (int c = 0; c < 3; ++c) {
#pragma unroll
        for (int cf = 0; cf < 4; ++cf) {
          bf16x8 kb = *(const bf16x8*)&Klds[cf * 16 + lr][c * 32 + koff];
          sc[0][cf] = __builtin_amdgcn_mfma_f32_16x16x32_bf16(qf[0][c], kb, sc[0][cf], 0, 0, 0);
          sc[1][cf] = __builtin_amdgcn_mfma_f32_16x16x32_bf16(qf[1][c], kb, sc[1][cf], 0, 0, 0);
        }
      }

#pragma unroll
      for (int hh = 0; hh < 2; ++hh) {
        if (!fullvis) {
          const int rowg = rowbase + hh * 16 + lg * 4;
#pragma unroll
          for (int cf = 0; cf < 4; ++cf) {
            const int colg = kt * 64 + cf * 16 + lr;
#pragma unroll
            for (int r = 0; r < 4; ++r)
              if (colg > rowg + r) sc[hh][cf][r] = -1.0e30f;
          }
        }
        float mx[4];
#pragma unroll
        for (int r = 0; r < 4; ++r) {
          float v = fmaxf(fmaxf(sc[hh][0][r], sc[hh][1][r]),
                          fmaxf(sc[hh][2][r], sc[hh][3][r]));
#pragma unroll
          for (int off = 1; off < 16; off <<= 1) v = fmaxf(v, __shfl_xor(v, off, 64));
          mx[r] = v;
        }
        bool need = false;  // T13 defer-max (log2 domain: 11.54 == e^8 bound)
#pragma unroll
        for (int r = 0; r < 4; ++r) need |= (mx[r] > m[hh][r] + 11.54f);
        if (__ballot(need)) {
          float al[4];
#pragma unroll
          for (int r = 0; r < 4; ++r) {
            const float mn = fmaxf(m[hh][r], mx[r]);
            al[r] = exp2f(m[hh][r] - mn);
            m[hh][r] = mn;
          }
#pragma unroll
          for (int d = 0; d < 5; ++d)
#pragma unroll
            for (int r = 0; r < 4; ++r) of[hh][d][r] *= al[r];
#pragma unroll
          for (int r = 0; r < 4; ++r) l[hh][r] *= al[r];
        }
        float ls[4] = {0.f, 0.f, 0.f, 0.f};
#pragma unroll
        for (int cf = 0; cf < 4; ++cf)
#pragma unroll
          for (int r = 0; r < 4; ++r) {
            const float p = exp2f(sc[hh][cf][r] - m[hh][r]);
            sc[hh][cf][r] = p;
            ls[r] += p;
          }
#pragma unroll
        for (int r = 0; r < 4; ++r) {
          float sv = ls[r];
#pragma unroll
          for (int off = 1; off < 16; off <<= 1) sv += __shfl_xor(sv, off, 64);
          l[hh][r] += sv;
        }
#pragma unroll
        for (int cf = 0; cf < 4; ++cf)
#pragma unroll
          for (int r = 0; r < 4; ++r)
            Plds[w][hh * 16 + lg * 4 + r][cf * 16 + lr] = f2bf(sc[hh][cf][r]);
      }

#pragma unroll
      for (int kc = 0; kc < 2; ++kc) {
        bf16x8 pa0 = *(const bf16x8*)&Plds[w][lr][kc * 32 + koff];
        bf16x8 pa1 = *(const bf16x8*)&Plds[w][16 + lr][kc * 32 + koff];
#pragma unroll
        for (int d = 0; d < 5; ++d) {
          bf16x8 vb = *(const bf16x8*)&Vt[d * 16 + lr][kc * 32 + koff];
          of[0][d] = __builtin_amdgcn_mfma_f32_16x16x32_bf16(pa0, vb, of[0][d], 0, 0, 0);
          of[1][d] = __builtin_amdgcn_mfma_f32_16x16x32_bf16(pa1, vb, of[1][d], 0, 0, 0);
        }
      }
    }

#pragma unroll
    for (int hh = 0; hh < 2; ++hh) {
      const int t = (bh >> 5) * SEQ + rowbase + hh * 16 + lg * 4;
#pragma unroll
      for (int r = 0; r < 4; ++r) {
        const float rl = 1.0f / l[hh][r];
#pragma unroll
        for (int d = 0; d < 5; ++d)
          Ob[(t + r) * HID + h * DH + d * 16 + lr] = f2bf(of[hh][d][r] * rl);
      }
    }
  }
}

// ---------------- launch ----------------
extern "C" void kernel_launch(void* const* d_in, const int* in_sizes, int n_in,
                              void* d_out, int out_size, void* d_ws, size_t ws_size,
                              hipStream_t stream) {
  const float* hs = (const float*)d_in[0];
  const float* cosb = (const float*)d_in[1];
  const float* sinb = (const float*)d_in[2];
  const float* w_qkv = (const float*)d_in[3];
  const float* b_qkv = (const float*)d_in[4];
  const float* w_dense = (const float*)d_in[5];
  const float* b_dense = (const float*)d_in[6];
  float* out = (float*)d_out;
  char* ws = (char*)d_ws;

  unsigned short* hsb = (unsigned short*)(ws + 0);          // 21.0 MB
  unsigned short* aob = (unsigned short*)(ws + 0);          // alias (attn out)
  unsigned short* wqb = (unsigned short*)(ws + 20971520);   // 39.3 MB
  unsigned short* wdb2 = (unsigned short*)(ws + 123207680); // 13.1 MB (dense W)
  unsigned short* Qb = (unsigned short*)(ws + 60293120);    // 21.0 MB
  unsigned short* Kb = (unsigned short*)(ws + 81264640);    // 21.0 MB
  unsigned short* Vb = (unsigned short*)(ws + 102236160);   // 21.0 MB ([B][H][D][S])

  cvt3_kernel<<<2048, 256, 0, stream>>>(hs, hsb, (NT * HID) / 4,
                                        w_qkv, wqb, (NQKV * HID) / 4,
                                        w_dense, wdb2, (HID * HID) / 4);
  gemm8p_kernel<0><<<dim3(NQKV / 256, NT / 256), 512, 0, stream>>>(
      hsb, wqb, b_qkv, Qb, Kb, Vb, nullptr, NT, NQKV, HID);
  rope_kernel<<<(NB * NH * SEQ * 16) / 256, 256, 0, stream>>>(Qb, Kb, cosb, sinb);
  attn_kernel<<<dim3(2, NB * NH), 512, 0, stream>>>(Qb, Kb, Vb, aob);
  gemmd8p_kernel<<<dim3(HID / 320, NT / 128), 512, 0, stream>>>(
      aob, wdb2, b_dense, out, NT, HID, HID);
}